// Round 1
// baseline (1733.659 us; speedup 1.0000x reference)
//
#include <hip/hip_runtime.h>
#include <math.h>

#define BB 4
#define HH 8
#define TT 4096
#define DD 64
#define NCC 64
#define WSZW 128
#define MEMN 1
#define KVW (MEMN + WSZW)   // 129
constexpr float EPSF = 1e-5f;
constexpr float SCALE = 0.125f;  // 64^-0.5

// ---------------- Kernel A: dists (f64 accum) + argmax + aux partial ----------------
__global__ __launch_bounds__(256) void dists_kernel(
    const float* __restrict__ q, const float* __restrict__ k,
    const float* __restrict__ means,
    float* __restrict__ distsQ, float* __restrict__ distsK,
    float* __restrict__ aux_sum)
{
    __shared__ float mS[NCC * 65];   // +1 pad: bank = (c+d)%32 -> 2-way max (free)
    const int chunks = (2 * TT) / 64;           // 128
    int bid = blockIdx.x;                       // B*H*chunks = 4096
    int bh = bid / chunks;
    int chunk = bid % chunks;
    int h = bh % HH;

    for (int i = threadIdx.x; i < NCC * DD; i += 256) {
        int c = i >> 6, d = i & 63;
        mS[c * 65 + d] = means[(h * NCC + c) * DD + d];
    }
    __syncthreads();

    int wave = threadIdx.x >> 6;
    int lane = threadIdx.x & 63;
    double auxAcc = 0.0;

    for (int i = 0; i < 16; ++i) {
        int l2 = chunk * 64 + wave * 16 + i;
        const float* src; float* dst; int l;
        if (l2 < TT) { l = l2;      src = q + ((size_t)bh * TT + l) * DD; dst = distsQ; }
        else         { l = l2 - TT; src = k + ((size_t)bh * TT + l) * DD; dst = distsK; }
        float x = src[lane];

        // ||x||^2 in f64 via butterfly
        double nx = (double)x * (double)x;
        #pragma unroll
        for (int off = 32; off; off >>= 1) nx += __shfl_xor(nx, off);
        double inv = 1.0 / fmax(sqrt(nx), 1e-12);

        // lane as cluster c: dot(x, means[c]) in f64
        double acc = 0.0;
        #pragma unroll
        for (int d = 0; d < DD; ++d) {
            float xd = __shfl(x, d);
            acc += (double)xd * (double)mS[lane * 65 + d];
        }
        float dist = (float)(acc * inv);
        dst[((size_t)(bh * NCC) + lane) * TT + l] = dist;

        // argmax over c (prefer lower index on tie, like jnp.argmax)
        float bv = dist; int bc = lane;
        #pragma unroll
        for (int off = 32; off; off >>= 1) {
            float ov = __shfl_xor(bv, off);
            int   oc = __shfl_xor(bc, off);
            if (ov > bv || (ov == bv && oc < bc)) { bv = ov; bc = oc; }
        }
        // aux term: lane as d
        float xn = (float)((double)x * inv);
        float diff = xn - mS[bc * 65 + lane];
        double a = (double)diff * (double)diff;
        #pragma unroll
        for (int off = 32; off; off >>= 1) a += __shfl_xor(a, off);
        if (lane == 0) auxAcc += a;
    }
    if (lane == 0) atomicAdd(aux_sum, (float)auxAcc);
}

// ---------------- Kernel B: top-128 per row via 4-pass radix select ----------------
__global__ __launch_bounds__(256) void topk_kernel(
    const float* __restrict__ dists, int* __restrict__ idxOut)
{
    int row = blockIdx.x;                       // bh*NC + c
    const float* dv = dists + (size_t)row * TT;
    int t = threadIdx.x;

    unsigned u[16];
    #pragma unroll
    for (int j = 0; j < 16; ++j) {
        unsigned b = __float_as_uint(dv[j * 256 + t]);
        u[j] = (b & 0x80000000u) ? ~b : (b | 0x80000000u);  // monotone map
    }

    __shared__ int hist[256];
    __shared__ int sfx[256];
    __shared__ int binSel, tgtS;
    __shared__ int nGtS, posS, eqFilled;
    __shared__ int waveCnt[4];

    int target = WSZW;
    unsigned prefix = 0;

    for (int shift = 24; shift >= 0; shift -= 8) {
        hist[t] = 0;
        __syncthreads();
        #pragma unroll
        for (int j = 0; j < 16; ++j) {
            bool act = (shift == 24) || ((u[j] >> (shift + 8)) == (prefix >> (shift + 8)));
            if (act) atomicAdd(&hist[(u[j] >> shift) & 255], 1);
        }
        __syncthreads();
        sfx[t] = hist[t];
        __syncthreads();
        for (int off = 1; off < 256; off <<= 1) {
            int add = (t + off < 256) ? sfx[t + off] : 0;
            int cur = sfx[t];
            __syncthreads();
            sfx[t] = cur + add;
            __syncthreads();
        }
        int nxt = (t == 255) ? 0 : sfx[t + 1];
        if (sfx[t] >= target && nxt < target) { binSel = t; tgtS = target - nxt; }
        __syncthreads();
        prefix |= ((unsigned)binSel) << shift;
        target = tgtS;
        __syncthreads();
    }

    unsigned pivot = prefix;
    if (t == 0) { nGtS = 0; posS = 0; eqFilled = 0; }
    __syncthreads();
    int myg = 0;
    #pragma unroll
    for (int j = 0; j < 16; ++j) myg += (u[j] > pivot) ? 1 : 0;
    if (myg) atomicAdd(&nGtS, myg);
    __syncthreads();
    int n_gt = nGtS;
    int n_need = WSZW - n_gt;
    int* out = idxOut + (size_t)row * WSZW;

    #pragma unroll
    for (int j = 0; j < 16; ++j)
        if (u[j] > pivot) { int p = atomicAdd(&posS, 1); out[p] = j * 256 + t; }

    // fill ties in ascending index order (jax tie-break: lower index first)
    int lane = t & 63, wv = t >> 6;
    for (int j = 0; j < 16; ++j) {
        if (eqFilled >= n_need) break;
        bool fl = (u[j] == pivot);
        unsigned long long bal = __ballot(fl);
        if (lane == 0) waveCnt[wv] = __popcll(bal);
        __syncthreads();
        int offw = 0;
        for (int w = 0; w < wv; ++w) offw += waveCnt[w];
        int mypos = eqFilled + offw + __popcll(bal & ((lane ? ((1ull << lane) - 1ull) : 0ull)));
        if (fl && mypos < n_need) out[n_gt + mypos] = j * 256 + t;
        __syncthreads();
        if (t == 0) eqFilled += waveCnt[0] + waveCnt[1] + waveCnt[2] + waveCnt[3];
        __syncthreads();
    }
}

// ---------------- Kernel C: per-cluster attention, online softmax ----------------
__global__ __launch_bounds__(128) void attn_kernel(
    const float* __restrict__ q, const float* __restrict__ k, const float* __restrict__ v,
    const float* __restrict__ mem_key, const float* __restrict__ mem_value,
    const int* __restrict__ idxQ, const int* __restrict__ idxK,
    float* __restrict__ numer, float* __restrict__ denom)
{
    int blk = blockIdx.x;        // bh*NC + c
    int c = blk % NCC;
    int bh = blk / NCC;
    int h = bh % HH;

    __shared__ int qiS[WSZW], kiS[WSZW];
    __shared__ float kS[16][DD], vS[16][DD];
    int tid = threadIdx.x;
    qiS[tid] = idxQ[(size_t)blk * WSZW + tid];
    kiS[tid] = idxK[(size_t)blk * WSZW + tid];
    __syncthreads();

    int tq = qiS[tid];
    const float* qrow = q + ((size_t)bh * TT + tq) * DD;
    float qr[DD];
    #pragma unroll
    for (int d0 = 0; d0 < DD; d0 += 4) {
        float4 f = *(const float4*)(qrow + d0);
        qr[d0] = f.x; qr[d0+1] = f.y; qr[d0+2] = f.z; qr[d0+3] = f.w;
    }
    float o[DD];
    #pragma unroll
    for (int d = 0; d < DD; ++d) o[d] = 0.f;
    float m = -1e30f, s = 0.f;

    for (int j0 = 0; j0 < KVW; j0 += 16) {
        int nrows = min(16, KVW - j0);
        {
            int r = tid >> 3;        // 16 rows x 8 threads
            int part = tid & 7;
            if (r < nrows) {
                int j = j0 + r;
                const float *ksrc, *vsrc;
                if (j == 0) {
                    ksrc = mem_key   + ((size_t)h * NCC + c) * (MEMN * DD);
                    vsrc = mem_value + ((size_t)h * NCC + c) * (MEMN * DD);
                } else {
                    int tk = kiS[j - 1];
                    ksrc = k + ((size_t)bh * TT + tk) * DD;
                    vsrc = v + ((size_t)bh * TT + tk) * DD;
                }
                float4 a  = *(const float4*)(ksrc + part * 8);
                float4 b2 = *(const float4*)(ksrc + part * 8 + 4);
                *(float4*)(&kS[r][part * 8])     = a;
                *(float4*)(&kS[r][part * 8 + 4]) = b2;
                a  = *(const float4*)(vsrc + part * 8);
                b2 = *(const float4*)(vsrc + part * 8 + 4);
                *(float4*)(&vS[r][part * 8])     = a;
                *(float4*)(&vS[r][part * 8 + 4]) = b2;
            }
        }
        __syncthreads();
        for (int jj = 0; jj < nrows; ++jj) {
            float dot = 0.f;
            #pragma unroll
            for (int d = 0; d < DD; ++d) dot += qr[d] * kS[jj][d];
            dot *= SCALE;
            if (dot > m) {
                float f = __expf(m - dot);
                s *= f;
                #pragma unroll
                for (int d = 0; d < DD; ++d) o[d] *= f;
                m = dot;
            }
            float w = __expf(dot - m);
            s += w;
            #pragma unroll
            for (int d = 0; d < DD; ++d) o[d] += w * vS[jj][d];
        }
        __syncthreads();
    }

    float invs = 1.f / s;
    float* np_ = numer + ((size_t)bh * TT + tq) * DD;
    #pragma unroll
    for (int d = 0; d < DD; ++d) atomicAdd(np_ + d, o[d] * invs);
    atomicAdd(denom + (size_t)bh * TT + tq, 1.f);
}

// ---------------- Kernel D: finalize ----------------
__global__ __launch_bounds__(256) void finalize_kernel(
    float* __restrict__ out, const float* __restrict__ denom,
    const float* __restrict__ aux_sum)
{
    size_t N = (size_t)BB * HH * TT * DD;
    size_t i = (size_t)blockIdx.x * 256 + threadIdx.x;
    if (i < N) out[i] = out[i] / (denom[i >> 6] + EPSF);
    if (i == 0) out[N] = aux_sum[0] * (1.0f / (float)(BB * HH * 2 * TT * DD));
}

extern "C" void kernel_launch(void* const* d_in, const int* in_sizes, int n_in,
                              void* d_out, int out_size, void* d_ws, size_t ws_size,
                              hipStream_t stream) {
    const float* q        = (const float*)d_in[0];
    const float* k        = (const float*)d_in[1];
    const float* v        = (const float*)d_in[2];
    const float* means    = (const float*)d_in[3];
    const float* mem_key  = (const float*)d_in[4];
    const float* mem_val  = (const float*)d_in[5];
    float* out = (float*)d_out;

    const size_t N = (size_t)BB * HH * TT * DD;             // 8388608
    const size_t nRows = (size_t)BB * HH * NCC;             // 2048
    float* wsf    = (float*)d_ws;
    float* distsQ = wsf;                                    // 8388608 f
    float* distsK = distsQ + (size_t)BB * HH * NCC * TT;    // 8388608 f
    float* denom  = distsK + (size_t)BB * HH * NCC * TT;    // 131072 f
    float* aux    = denom + (size_t)BB * HH * TT;           // 1 f
    int*   idxQ   = (int*)(aux + 1);                        // 262144 i
    int*   idxK   = idxQ + nRows * WSZW;                    // 262144 i

    // zero numer (in d_out) + aux slot; zero denom + aux
    hipMemsetAsync(d_out, 0, (N + 1) * sizeof(float), stream);
    hipMemsetAsync(denom, 0, ((size_t)BB * HH * TT + 1) * sizeof(float), stream);

    dists_kernel<<<dim3(BB * HH * (2 * TT / 64)), dim3(256), 0, stream>>>(
        q, k, means, distsQ, distsK, aux);
    topk_kernel<<<dim3((unsigned)nRows), dim3(256), 0, stream>>>(distsQ, idxQ);
    topk_kernel<<<dim3((unsigned)nRows), dim3(256), 0, stream>>>(distsK, idxK);
    attn_kernel<<<dim3((unsigned)nRows), dim3(128), 0, stream>>>(
        q, k, v, mem_key, mem_val, idxQ, idxK, out, denom);
    finalize_kernel<<<dim3((unsigned)((N + 256) / 256)), dim3(256), 0, stream>>>(
        out, denom, aux);
}

// Round 2
// 1698.546 us; speedup vs baseline: 1.0207x; 1.0207x over previous
//
#include <hip/hip_runtime.h>
#include <math.h>

#define BB 4
#define HH 8
#define TT 4096
#define DD 64
#define NCC 64
#define WSZW 128
#define MEMN 1
#define KVW (MEMN + WSZW)   // 129
constexpr float EPSF = 1e-5f;
constexpr float SCALE = 0.125f;  // 64^-0.5

// ---------------- Kernel A: dists (f64 accum) + argmax + aux partial ----------------
__global__ __launch_bounds__(256) void dists_kernel(
    const float* __restrict__ q, const float* __restrict__ k,
    const float* __restrict__ means,
    float* __restrict__ distsQ, float* __restrict__ distsK,
    float* __restrict__ aux_sum)
{
    __shared__ float mS[NCC * 65];   // +1 pad: bank = (c+d)%32 -> 2-way max (free)
    const int chunks = (2 * TT) / 64;           // 128
    int bid = blockIdx.x;                       // B*H*chunks = 4096
    int bh = bid / chunks;
    int chunk = bid % chunks;
    int h = bh % HH;

    for (int i = threadIdx.x; i < NCC * DD; i += 256) {
        int c = i >> 6, d = i & 63;
        mS[c * 65 + d] = means[(h * NCC + c) * DD + d];
    }
    __syncthreads();

    int wave = threadIdx.x >> 6;
    int lane = threadIdx.x & 63;
    double auxAcc = 0.0;

    for (int i = 0; i < 16; ++i) {
        int l2 = chunk * 64 + wave * 16 + i;
        const float* src; float* dst; int l;
        if (l2 < TT) { l = l2;      src = q + ((size_t)bh * TT + l) * DD; dst = distsQ; }
        else         { l = l2 - TT; src = k + ((size_t)bh * TT + l) * DD; dst = distsK; }
        float x = src[lane];

        // ||x||^2 in f64 via butterfly
        double nx = (double)x * (double)x;
        #pragma unroll
        for (int off = 32; off; off >>= 1) nx += __shfl_xor(nx, off);
        double inv = 1.0 / fmax(sqrt(nx), 1e-12);

        // lane as cluster c: dot(x, means[c]) in f64
        double acc = 0.0;
        #pragma unroll
        for (int d = 0; d < DD; ++d) {
            float xd = __shfl(x, d);
            acc += (double)xd * (double)mS[lane * 65 + d];
        }
        float dist = (float)(acc * inv);
        dst[((size_t)(bh * NCC) + lane) * TT + l] = dist;

        // argmax over c (prefer lower index on tie, like jnp.argmax)
        float bv = dist; int bc = lane;
        #pragma unroll
        for (int off = 32; off; off >>= 1) {
            float ov = __shfl_xor(bv, off);
            int   oc = __shfl_xor(bc, off);
            if (ov > bv || (ov == bv && oc < bc)) { bv = ov; bc = oc; }
        }
        // aux term: lane as d
        float xn = (float)((double)x * inv);
        float diff = xn - mS[bc * 65 + lane];
        double a = (double)diff * (double)diff;
        #pragma unroll
        for (int off = 32; off; off >>= 1) a += __shfl_xor(a, off);
        if (lane == 0) auxAcc += a;
    }
    if (lane == 0) atomicAdd(aux_sum, (float)auxAcc);
}

// ---------------- Kernel B: top-128 per row via 4-pass radix select ----------------
__global__ __launch_bounds__(256) void topk_kernel(
    const float* __restrict__ dists, int* __restrict__ idxOut)
{
    int row = blockIdx.x;                       // bh*NC + c
    const float* dv = dists + (size_t)row * TT;
    int t = threadIdx.x;

    unsigned u[16];
    #pragma unroll
    for (int j = 0; j < 16; ++j) {
        unsigned b = __float_as_uint(dv[j * 256 + t]);
        u[j] = (b & 0x80000000u) ? ~b : (b | 0x80000000u);  // monotone map
    }

    __shared__ int hist[256];
    __shared__ int sfx[256];
    __shared__ int binSel, tgtS;
    __shared__ int nGtS, posS, eqFilled;
    __shared__ int waveCnt[4];

    int target = WSZW;
    unsigned prefix = 0;

    for (int shift = 24; shift >= 0; shift -= 8) {
        hist[t] = 0;
        __syncthreads();
        #pragma unroll
        for (int j = 0; j < 16; ++j) {
            bool act = (shift == 24) || ((u[j] >> (shift + 8)) == (prefix >> (shift + 8)));
            if (act) atomicAdd(&hist[(u[j] >> shift) & 255], 1);
        }
        __syncthreads();
        sfx[t] = hist[t];
        __syncthreads();
        for (int off = 1; off < 256; off <<= 1) {
            int add = (t + off < 256) ? sfx[t + off] : 0;
            int cur = sfx[t];
            __syncthreads();
            sfx[t] = cur + add;
            __syncthreads();
        }
        int nxt = (t == 255) ? 0 : sfx[t + 1];
        if (sfx[t] >= target && nxt < target) { binSel = t; tgtS = target - nxt; }
        __syncthreads();
        prefix |= ((unsigned)binSel) << shift;
        target = tgtS;
        __syncthreads();
    }

    unsigned pivot = prefix;
    if (t == 0) { nGtS = 0; posS = 0; eqFilled = 0; }
    __syncthreads();
    int myg = 0;
    #pragma unroll
    for (int j = 0; j < 16; ++j) myg += (u[j] > pivot) ? 1 : 0;
    if (myg) atomicAdd(&nGtS, myg);
    __syncthreads();
    int n_gt = nGtS;
    int n_need = WSZW - n_gt;
    int* out = idxOut + (size_t)row * WSZW;

    #pragma unroll
    for (int j = 0; j < 16; ++j)
        if (u[j] > pivot) { int p = atomicAdd(&posS, 1); out[p] = j * 256 + t; }

    // fill ties in ascending index order (jax tie-break: lower index first)
    int lane = t & 63, wv = t >> 6;
    for (int j = 0; j < 16; ++j) {
        if (eqFilled >= n_need) break;
        bool fl = (u[j] == pivot);
        unsigned long long bal = __ballot(fl);
        if (lane == 0) waveCnt[wv] = __popcll(bal);
        __syncthreads();
        int offw = 0;
        for (int w = 0; w < wv; ++w) offw += waveCnt[w];
        int mypos = eqFilled + offw + __popcll(bal & ((lane ? ((1ull << lane) - 1ull) : 0ull)));
        if (fl && mypos < n_need) out[n_gt + mypos] = j * 256 + t;
        __syncthreads();
        if (t == 0) eqFilled += waveCnt[0] + waveCnt[1] + waveCnt[2] + waveCnt[3];
        __syncthreads();
    }
}

// ---------------- Kernel C: per-cluster attention, 2 lanes per q-row ----------------
// 256 threads = 4 waves; wave w handles q-rows w*32..w*32+31; lane pair (2i,2i+1)
// owns row i's d-halves. KV processed in 4 chunks of 33 rows (129 padded to 132),
// two-pass per chunk: dots -> single rescale -> exp+accumulate.
__global__ __launch_bounds__(256) void attn_kernel(
    const float* __restrict__ q, const float* __restrict__ k, const float* __restrict__ v,
    const float* __restrict__ mem_key, const float* __restrict__ mem_value,
    const int* __restrict__ idxQ, const int* __restrict__ idxK,
    float* __restrict__ numer, float* __restrict__ denom)
{
    int blk = blockIdx.x;        // bh*NC + c
    int c = blk % NCC;
    int bh = blk / NCC;
    int h = bh % HH;

    __shared__ int kiS[WSZW];
    __shared__ float kS[33][68];   // row pad 68: staging writes spread banks
    __shared__ float vS[33][68];

    int tid = threadIdx.x;
    if (tid < WSZW) kiS[tid] = idxK[(size_t)blk * WSZW + tid];
    __syncthreads();

    int wv = tid >> 6, lane = tid & 63;
    int r = wv * 32 + (lane >> 1);
    int half = lane & 1;
    int tq = idxQ[(size_t)blk * WSZW + r];
    const float* qrow = q + ((size_t)bh * TT + tq) * DD + half * 32;
    float qh[32];
    #pragma unroll
    for (int d0 = 0; d0 < 32; d0 += 4) {
        float4 f = *(const float4*)(qrow + d0);
        qh[d0] = f.x; qh[d0+1] = f.y; qh[d0+2] = f.z; qh[d0+3] = f.w;
    }
    float oh[32];
    #pragma unroll
    for (int d = 0; d < 32; ++d) oh[d] = 0.f;
    float m = -1e30f, s = 0.f;

    for (int ci = 0; ci < 4; ++ci) {
        int jbase = ci * 33;
        // stage 33 kv rows (8 threads per row, 8 floats each)
        for (int idx = tid; idx < 33 * 8; idx += 256) {
            int rr = idx >> 3, part = idx & 7;
            int j = jbase + rr;
            float4 ka = {0,0,0,0}, kb = {0,0,0,0}, va = {0,0,0,0}, vb = {0,0,0,0};
            if (j < KVW) {
                const float *ksrc, *vsrc;
                if (j == 0) {
                    ksrc = mem_key   + ((size_t)h * NCC + c) * (MEMN * DD);
                    vsrc = mem_value + ((size_t)h * NCC + c) * (MEMN * DD);
                } else {
                    int tk = kiS[j - 1];
                    ksrc = k + ((size_t)bh * TT + tk) * DD;
                    vsrc = v + ((size_t)bh * TT + tk) * DD;
                }
                ka = *(const float4*)(ksrc + part * 8);
                kb = *(const float4*)(ksrc + part * 8 + 4);
                va = *(const float4*)(vsrc + part * 8);
                vb = *(const float4*)(vsrc + part * 8 + 4);
            }
            *(float4*)(&kS[rr][part * 8])     = ka;
            *(float4*)(&kS[rr][part * 8 + 4]) = kb;
            *(float4*)(&vS[rr][part * 8])     = va;
            *(float4*)(&vS[rr][part * 8 + 4]) = vb;
        }
        __syncthreads();

        // pass 1: all 33 dots (statically indexed reg array)
        float dt[33];
        #pragma unroll
        for (int jj = 0; jj < 33; ++jj) {
            float acc = 0.f;
            const float* kr = &kS[jj][half * 32];
            #pragma unroll
            for (int d = 0; d < 32; ++d) acc += qh[d] * kr[d];
            acc += __shfl_xor(acc, 1);
            dt[jj] = acc * SCALE;   // padded rows -> 0; safe (m just shifts)
        }
        // single rescale per chunk
        float cm = m;
        #pragma unroll
        for (int jj = 0; jj < 33; ++jj) cm = fmaxf(cm, dt[jj]);
        float f = __expf(m - cm);
        s *= f;
        #pragma unroll
        for (int d = 0; d < 32; ++d) oh[d] *= f;
        m = cm;
        // pass 2: exp + accumulate
        #pragma unroll
        for (int jj = 0; jj < 33; ++jj) {
            int j = jbase + jj;
            float w = (j < KVW) ? __expf(dt[jj] - m) : 0.f;
            s += w;
            const float* vr = &vS[jj][half * 32];
            #pragma unroll
            for (int d = 0; d < 32; ++d) oh[d] += w * vr[d];
        }
        __syncthreads();
    }

    float invs = 1.f / s;   // s identical across the lane pair
    float* np_ = numer + ((size_t)bh * TT + tq) * DD + half * 32;
    #pragma unroll
    for (int d = 0; d < 32; ++d) atomicAdd(np_ + d, oh[d] * invs);
    if (half == 0) atomicAdd(denom + (size_t)bh * TT + tq, 1.f);
}

// ---------------- Kernel D: finalize ----------------
__global__ __launch_bounds__(256) void finalize_kernel(
    float* __restrict__ out, const float* __restrict__ denom,
    const float* __restrict__ aux_sum)
{
    size_t N = (size_t)BB * HH * TT * DD;
    size_t i = (size_t)blockIdx.x * 256 + threadIdx.x;
    if (i < N) out[i] = out[i] / (denom[i >> 6] + EPSF);
    if (i == 0) out[N] = aux_sum[0] * (1.0f / (float)(BB * HH * 2 * TT * DD));
}

extern "C" void kernel_launch(void* const* d_in, const int* in_sizes, int n_in,
                              void* d_out, int out_size, void* d_ws, size_t ws_size,
                              hipStream_t stream) {
    const float* q        = (const float*)d_in[0];
    const float* k        = (const float*)d_in[1];
    const float* v        = (const float*)d_in[2];
    const float* means    = (const float*)d_in[3];
    const float* mem_key  = (const float*)d_in[4];
    const float* mem_val  = (const float*)d_in[5];
    float* out = (float*)d_out;

    const size_t N = (size_t)BB * HH * TT * DD;             // 8388608
    const size_t nRows = (size_t)BB * HH * NCC;             // 2048
    float* wsf    = (float*)d_ws;
    float* distsQ = wsf;                                    // 8388608 f
    float* distsK = distsQ + (size_t)BB * HH * NCC * TT;    // 8388608 f
    float* denom  = distsK + (size_t)BB * HH * NCC * TT;    // 131072 f
    float* aux    = denom + (size_t)BB * HH * TT;           // 1 f
    int*   idxQ   = (int*)(aux + 1);                        // 262144 i
    int*   idxK   = idxQ + nRows * WSZW;                    // 262144 i

    // zero numer (in d_out) + aux slot; zero denom + aux
    hipMemsetAsync(d_out, 0, (N + 1) * sizeof(float), stream);
    hipMemsetAsync(denom, 0, ((size_t)BB * HH * TT + 1) * sizeof(float), stream);

    dists_kernel<<<dim3(BB * HH * (2 * TT / 64)), dim3(256), 0, stream>>>(
        q, k, means, distsQ, distsK, aux);
    topk_kernel<<<dim3((unsigned)nRows), dim3(256), 0, stream>>>(distsQ, idxQ);
    topk_kernel<<<dim3((unsigned)nRows), dim3(256), 0, stream>>>(distsK, idxK);
    attn_kernel<<<dim3((unsigned)nRows), dim3(256), 0, stream>>>(
        q, k, v, mem_key, mem_val, idxQ, idxK, out, denom);
    finalize_kernel<<<dim3((unsigned)((N + 256) / 256)), dim3(256), 0, stream>>>(
        out, denom, aux);
}